// Round 11
// baseline (123.400 us; speedup 1.0000x reference)
//
#include <hip/hip_runtime.h>

#define N    1024
#define HD   64
#define MD   32
#define BLK  256        // k_p0 block
#define BLKP 512        // pair-kernel block: 8 waves -> 4 waves/SIMD resident
#define WROW (2 * HD + 1)   // 129, w_msg row stride

// ---------------------------------------------------------------------------
// P0: h0 = feat + posenc; A1/B1 projections. One block per 4 rows.
// ---------------------------------------------------------------------------
__global__ __launch_bounds__(BLK) void k_p0(const float* __restrict__ feat,
                                            const float* __restrict__ wmsg,
                                            const float* __restrict__ bmsg,
                                            float* __restrict__ h0,
                                            float* __restrict__ A,
                                            float* __restrict__ Bb)
{
    __shared__ float scr[4160 + 4 * HD];
    const int tid = threadIdx.x;
    const int n0  = blockIdx.x * 4;

    for (int u = tid; u < MD * WROW; u += BLK) scr[u] = wmsg[u];   // 4128 floats
    float* hrow = scr + 4160;
    {
        const int n = n0 + (tid >> 6), d = tid & 63;
        const float div = expf((float)(d & ~1) * (-9.210340371976184f / 64.0f));
        const float ang = (float)n * div;
        const float pe  = (d & 1) ? cosf(ang) : sinf(ang);
        const float hv  = feat[n * HD + d] + pe;
        h0[n * HD + d] = hv;
        hrow[tid] = hv;
    }
    __syncthreads();
    if (tid < 4 * MD) {
        const int nl = tid >> 5, m = tid & 31;
        const float* wa = scr + m * WROW;          // stride 129: conflict-free
        const float* hr = hrow + nl * HD;
        float sa = 0.f, sb = bmsg[m];
#pragma unroll
        for (int c = 0; c < HD; c++) {
            const float hv = hr[c];
            sa = fmaf(hv, wa[c], sa);
            sb = fmaf(hv, wa[HD + c], sb);
        }
        const int n = n0 + nl;
        A[n * MD + m]  = sa;
        Bb[n * MD + m] = sb;
    }
}

// ---------------------------------------------------------------------------
// Pair kernel: one block (512 thr = 8 waves) per row-pair (iA, iB = iA+N/2).
// Wave w owns j in [w*128, w*128+128).  Lane map: kq = lane>>3 (4 k's via one
// float4 A-load), jslot = lane&7 (8 j per wave-iter).
// IDEMPOTENT: reads its inputs, writes its outputs, no read-modify-write of
// global state -> safe to launch multiple times (used for the 4x ablation).
// ---------------------------------------------------------------------------
template<int LAYER1>
__global__ __launch_bounds__(BLKP) void k_pair(
    const float* __restrict__ xsrc, const float* __restrict__ Aap,
    const float* __restrict__ Bbp, const float* __restrict__ wmsg,
    const float* __restrict__ wpos, const float* __restrict__ bpos,
    float* __restrict__ xout,
    const float* __restrict__ h0, const float* __restrict__ wf,
    const float* __restrict__ bf, const float* __restrict__ wmsg2,
    const float* __restrict__ bmsg2, float* __restrict__ A2,
    float* __restrict__ B2)
{
    const int tid   = threadIdx.x;
    const int wid   = tid >> 6;         // 0..7
    const int lane  = tid & 63;
    const int jslot = lane & 7;
    const int kq    = lane >> 3;        // k = kq*4 .. kq*4+3

    __shared__ float4 rd[2 * N];        // 32 KB: rdA | rdB (contiguous scratch)
    __shared__ float  wacc[8][8];
    __shared__ float  msAl[8][MD];
    __shared__ float  msBl[8][MD];
    __shared__ float  SxL[3];
    __shared__ float  msF[2][MD];
    __shared__ float  h0r[2][HD];
    __shared__ float  h1r[2][HD];
    float4* rdA = rd;
    float4* rdB = rd + N;

    const int iA = blockIdx.x, iB = blockIdx.x + N / 2;
    const float xiA0 = xsrc[iA * 3 + 0], xiA1 = xsrc[iA * 3 + 1], xiA2 = xsrc[iA * 3 + 2];
    const float xiB0 = xsrc[iB * 3 + 0], xiB1 = xsrc[iB * 3 + 1], xiB2 = xsrc[iB * 3 + 2];

    // ---- stage r/d2 tables for both rows; accumulate column-sum of x ----
    float sx0 = 0.f, sx1 = 0.f, sx2 = 0.f;
#pragma unroll
    for (int q = 0; q < N / BLKP; q++) {
        const int j = q * BLKP + tid;
        const float xj0 = xsrc[j * 3 + 0];
        const float xj1 = xsrc[j * 3 + 1];
        const float xj2 = xsrc[j * 3 + 2];
        sx0 += xj0; sx1 += xj1; sx2 += xj2;
        float r0 = xj0 - xiA0, r1 = xj1 - xiA1, r2 = xj2 - xiA2;
        rdA[j] = make_float4(r0, r1, r2, fmaf(r0, r0, fmaf(r1, r1, r2 * r2)));
        r0 = xj0 - xiB0; r1 = xj1 - xiB1; r2 = xj2 - xiB2;
        rdB[j] = make_float4(r0, r1, r2, fmaf(r0, r0, fmaf(r1, r1, r2 * r2)));
    }
#pragma unroll
    for (int off = 32; off > 0; off >>= 1) {
        sx0 += __shfl_xor(sx0, off);
        sx1 += __shfl_xor(sx1, off);
        sx2 += __shfl_xor(sx2, off);
    }
    if (lane == 0) { wacc[wid][0] = sx0; wacc[wid][1] = sx1; wacc[wid][2] = sx2; }
    __syncthreads();                       // rd tables + sx partials ready
    if (tid == 0) {
        float s0 = 0.f, s1 = 0.f, s2 = 0.f;
#pragma unroll
        for (int w = 0; w < 8; w++) { s0 += wacc[w][0]; s1 += wacc[w][1]; s2 += wacc[w][2]; }
        SxL[0] = s0; SxL[1] = s1; SxL[2] = s2;
    }

    // ---- per-lane weights for the 4 owned k's ----
    const float4 biA4 = *(const float4*)(Bbp + iA * MD + kq * 4);
    const float4 biB4 = *(const float4*)(Bbp + iB * MD + kq * 4);
    const float4 wpx4 = *(const float4*)(wpos + kq * 4);
    const float4 wpy4 = *(const float4*)(wpos + MD + kq * 4);
    const float4 wpz4 = *(const float4*)(wpos + 2 * MD + kq * 4);
    float wd4[4];
#pragma unroll
    for (int kk = 0; kk < 4; kk++) wd4[kk] = wmsg[(kq * 4 + kk) * WROW + 2 * HD];
    const float biA[4] = {biA4.x, biA4.y, biA4.z, biA4.w};
    const float biB[4] = {biB4.x, biB4.y, biB4.z, biB4.w};
    const float wpx[4] = {wpx4.x, wpx4.y, wpx4.z, wpx4.w};
    const float wpy[4] = {wpy4.x, wpy4.y, wpy4.z, wpy4.w};
    const float wpz[4] = {wpz4.x, wpz4.y, wpz4.z, wpz4.w};

    float PAx[4] = {0,0,0,0}, PAy[4] = {0,0,0,0}, PAz[4] = {0,0,0,0};
    float PBx[4] = {0,0,0,0}, PBy[4] = {0,0,0,0}, PBz[4] = {0,0,0,0};
    float msA[4] = {0,0,0,0}, msB[4] = {0,0,0,0};

    const int jb = wid * (N / 8);          // 128 j per wave
#pragma unroll 8
    for (int it = 0; it < N / 8 / 8; it++) {
        const int j = jb + it * 8 + jslot;
        const float4 a4 = *(const float4*)(Aap + j * MD + kq * 4);
        const float4 fA = rdA[j];          // 8-way broadcast per address
        const float4 fB = rdB[j];
        const float av[4] = {a4.x, a4.y, a4.z, a4.w};
#pragma unroll
        for (int kk = 0; kk < 4; kk++) {
            const float mA = fmaxf(fmaf(fA.w, wd4[kk], av[kk] + biA[kk]), 0.f);
            const float mB = fmaxf(fmaf(fB.w, wd4[kk], av[kk] + biB[kk]), 0.f);
            if (LAYER1) { msA[kk] += mA; msB[kk] += mB; }
            PAx[kk] = fmaf(mA, fA.x, PAx[kk]);
            PAy[kk] = fmaf(mA, fA.y, PAy[kk]);
            PAz[kk] = fmaf(mA, fA.z, PAz[kk]);
            PBx[kk] = fmaf(mB, fB.x, PBx[kk]);
            PBy[kk] = fmaf(mB, fB.y, PBy[kk]);
            PBz[kk] = fmaf(mB, fB.z, PBz[kk]);
        }
    }

    // ---- fold wp per lane, then reduce across 64 lanes ----
    float vA0 = 0.f, vA1 = 0.f, vA2 = 0.f, vB0 = 0.f, vB1 = 0.f, vB2 = 0.f;
#pragma unroll
    for (int kk = 0; kk < 4; kk++) {
        vA0 = fmaf(PAx[kk], wpx[kk], vA0);
        vA1 = fmaf(PAy[kk], wpy[kk], vA1);
        vA2 = fmaf(PAz[kk], wpz[kk], vA2);
        vB0 = fmaf(PBx[kk], wpx[kk], vB0);
        vB1 = fmaf(PBy[kk], wpy[kk], vB1);
        vB2 = fmaf(PBz[kk], wpz[kk], vB2);
    }
#pragma unroll
    for (int off = 32; off > 0; off >>= 1) {
        vA0 += __shfl_xor(vA0, off); vA1 += __shfl_xor(vA1, off); vA2 += __shfl_xor(vA2, off);
        vB0 += __shfl_xor(vB0, off); vB1 += __shfl_xor(vB1, off); vB2 += __shfl_xor(vB2, off);
    }
    if (LAYER1) {
        // reduce msum over the 8 jslots (lane bits 0..2)
#pragma unroll
        for (int off = 1; off <= 4; off <<= 1) {
#pragma unroll
            for (int kk = 0; kk < 4; kk++) {
                msA[kk] += __shfl_xor(msA[kk], off);
                msB[kk] += __shfl_xor(msB[kk], off);
            }
        }
    }
    __syncthreads();                       // wacc consumed into SxL; reusable
    if (lane == 0) {
        wacc[wid][0] = vA0; wacc[wid][1] = vA1; wacc[wid][2] = vA2;
        wacc[wid][3] = vB0; wacc[wid][4] = vB1; wacc[wid][5] = vB2;
    }
    if (LAYER1 && jslot == 0) {
#pragma unroll
        for (int kk = 0; kk < 4; kk++) {
            msAl[wid][kq * 4 + kk] = msA[kk];
            msBl[wid][kq * 4 + kk] = msB[kk];
        }
    }
    __syncthreads();                       // epilogue data ready

    if (tid == 0) {
        const float bp0 = bpos[0], bp1 = bpos[1], bp2 = bpos[2];
        float aA0 = 0.f, aA1 = 0.f, aA2 = 0.f, aB0 = 0.f, aB1 = 0.f, aB2 = 0.f;
#pragma unroll
        for (int w = 0; w < 8; w++) {
            aA0 += wacc[w][0]; aA1 += wacc[w][1]; aA2 += wacc[w][2];
            aB0 += wacc[w][3]; aB1 += wacc[w][4]; aB2 += wacc[w][5];
        }
        const float inv = 1.0f / 1023.0f;
        xout[iA * 3 + 0] = xiA0 + (aA0 + bp0 * (SxL[0] - (float)N * xiA0)) * inv;
        xout[iA * 3 + 1] = xiA1 + (aA1 + bp1 * (SxL[1] - (float)N * xiA1)) * inv;
        xout[iA * 3 + 2] = xiA2 + (aA2 + bp2 * (SxL[2] - (float)N * xiA2)) * inv;
        xout[iB * 3 + 0] = xiB0 + (aB0 + bp0 * (SxL[0] - (float)N * xiB0)) * inv;
        xout[iB * 3 + 1] = xiB1 + (aB1 + bp1 * (SxL[1] - (float)N * xiB1)) * inv;
        xout[iB * 3 + 2] = xiB2 + (aB2 + bp2 * (SxL[2] - (float)N * xiB2)) * inv;
    }

    if (LAYER1) {
        // ---- fused h-update + layer-2 A/B projections for rows iA, iB ----
        float* scr = (float*)rd;           // 8192 floats free after main loop
        if (tid < 2 * MD) {                // msum rows with diagonal correction
            const int row = tid >> 5, k = tid & 31;
            const int i = row ? iB : iA;
            const float (*ml)[MD] = row ? msBl : msAl;
            float s = 0.f;
#pragma unroll
            for (int w = 0; w < 8; w++) s += ml[w][k];
            s -= fmaxf(Aap[i * MD + k] + Bbp[i * MD + k], 0.f);   // d2=0 at j==i
            msF[row][k] = s;
        }
        for (int u = tid; u < HD * (HD + MD); u += BLKP) {         // stage wf
            const int o = u / (HD + MD), c = u - o * (HD + MD);
            scr[o * 97 + c] = wf[u];
        }
        if (tid < 2 * HD) {
            const int row = tid >> 6, d = tid & 63;
            h0r[row][d] = h0[(row ? iB : iA) * HD + d];
        }
        __syncthreads();
        if (tid < 2 * HD) {                // h1 rows
            const int row = tid >> 6, o = tid & 63;
            const float* w = scr + o * 97;
            float s = bf[o];
#pragma unroll
            for (int c = 0; c < HD; c++) s = fmaf(h0r[row][c], w[c], s);
#pragma unroll
            for (int k = 0; k < MD; k++) s = fmaf(msF[row][k], w[HD + k], s);
            h1r[row][o] = fmaxf(s, 0.f);
        }
        __syncthreads();
        for (int u = tid; u < MD * WROW; u += BLKP) scr[u] = wmsg2[u];
        __syncthreads();
        if (tid < 2 * MD) {                // A2/B2 rows
            const int row = tid >> 5, m = tid & 31;
            const float* wa = scr + m * WROW;
            const float* hr = h1r[row];
            float sa = 0.f, sb = bmsg2[m];
#pragma unroll
            for (int c = 0; c < HD; c++) {
                const float hv = hr[c];
                sa = fmaf(hv, wa[c], sa);
                sb = fmaf(hv, wa[HD + c], sb);
            }
            const int i = row ? iB : iA;
            A2[i * MD + m] = sa;
            B2[i * MD + m] = sb;
        }
    }
}

// ---------------------------------------------------------------------------
// ABLATION ROUND: identical to the 39.7us round-9 kernels, but each pair
// kernel is launched 4x (idempotent, bit-identical outputs). With round-9's
// C + P = 39.7:   dur = C + 4P   =>   P = (dur - 39.7)/3.
// ---------------------------------------------------------------------------
extern "C" void kernel_launch(void* const* d_in, const int* in_sizes, int n_in,
                              void* d_out, int out_size, void* d_ws, size_t ws_size,
                              hipStream_t stream)
{
    const float* pos     = (const float*)d_in[0];
    const float* feat    = (const float*)d_in[1];
    const float* w_msg1  = (const float*)d_in[3];
    const float* b_msg1  = (const float*)d_in[4];
    const float* w_pos1  = (const float*)d_in[5];
    const float* b_pos1  = (const float*)d_in[6];
    const float* w_feat1 = (const float*)d_in[7];
    const float* b_feat1 = (const float*)d_in[8];
    const float* w_msg2  = (const float*)d_in[9];
    const float* b_msg2  = (const float*)d_in[10];
    const float* w_pos2  = (const float*)d_in[11];
    const float* b_pos2  = (const float*)d_in[12];

    float* ws  = (float*)d_ws;
    float* h0  = ws;                 // N*HD
    float* A1  = h0  + N * HD;       // N*MD
    float* B1  = A1  + N * MD;
    float* x1  = B1  + N * MD;       // N*4 (padded)
    float* A2  = x1  + N * 4;
    float* B2  = A2  + N * MD;

    k_p0<<<N / 4, BLK, 0, stream>>>(feat, w_msg1, b_msg1, h0, A1, B1);
    for (int r = 0; r < 4; r++)
        k_pair<1><<<N / 2, BLKP, 0, stream>>>(pos, A1, B1, w_msg1, w_pos1, b_pos1, x1,
                                              h0, w_feat1, b_feat1, w_msg2, b_msg2, A2, B2);
    for (int r = 0; r < 4; r++)
        k_pair<0><<<N / 2, BLKP, 0, stream>>>(x1, A2, B2, w_msg2, w_pos2, b_pos2,
                                              (float*)d_out,
                                              nullptr, nullptr, nullptr, nullptr,
                                              nullptr, nullptr, nullptr);
}

// Round 12
// 56.173 us; speedup vs baseline: 2.1968x; 2.1968x over previous
//
#include <hip/hip_runtime.h>

#define N    1024
#define HD   64
#define MD   32
#define BLK  256        // k_p0 / k_p2 block
#define BLKP 512        // pair-kernel block: 8 waves; 1024 blocks -> 8 waves/SIMD
#define WROW (2 * HD + 1)   // 129, w_msg row stride

// ---------------------------------------------------------------------------
// P0: h0 = feat + posenc; A1/B1 projections. One block per 4 rows.
// ---------------------------------------------------------------------------
__global__ __launch_bounds__(BLK) void k_p0(const float* __restrict__ feat,
                                            const float* __restrict__ wmsg,
                                            const float* __restrict__ bmsg,
                                            float* __restrict__ h0,
                                            float* __restrict__ A,
                                            float* __restrict__ Bb)
{
    __shared__ float scr[4160 + 4 * HD];
    const int tid = threadIdx.x;
    const int n0  = blockIdx.x * 4;

    for (int u = tid; u < MD * WROW; u += BLK) scr[u] = wmsg[u];   // 4128 floats
    float* hrow = scr + 4160;
    {
        const int n = n0 + (tid >> 6), d = tid & 63;
        const float div = expf((float)(d & ~1) * (-9.210340371976184f / 64.0f));
        const float ang = (float)n * div;
        const float pe  = (d & 1) ? cosf(ang) : sinf(ang);
        const float hv  = feat[n * HD + d] + pe;
        h0[n * HD + d] = hv;
        hrow[tid] = hv;
    }
    __syncthreads();
    if (tid < 4 * MD) {
        const int nl = tid >> 5, m = tid & 31;
        const float* wa = scr + m * WROW;          // stride 129: conflict-free
        const float* hr = hrow + nl * HD;
        float sa = 0.f, sb = bmsg[m];
#pragma unroll
        for (int c = 0; c < HD; c++) {
            const float hv = hr[c];
            sa = fmaf(hv, wa[c], sa);
            sb = fmaf(hv, wa[HD + c], sb);
        }
        const int n = n0 + nl;
        A[n * MD + m]  = sa;
        Bb[n * MD + m] = sb;
    }
}

// ---------------------------------------------------------------------------
// P2: h1 = relu([h0, ms1] @ wf.T + bf); A2/B2 projections. One block per 4 rows.
// ---------------------------------------------------------------------------
__global__ __launch_bounds__(BLK) void k_p2(const float* __restrict__ h0,
                                            const float* __restrict__ ms1,
                                            const float* __restrict__ wf,
                                            const float* __restrict__ bf,
                                            const float* __restrict__ wmsg,
                                            const float* __restrict__ bmsg,
                                            float* __restrict__ A,
                                            float* __restrict__ Bb)
{
    __shared__ float scr[6848];
    const int tid = threadIdx.x;
    const int n0  = blockIdx.x * 4;

    float* wbig = scr;                  // 64 rows, padded stride 97 -> 6208
    float* h0r  = scr + 6208;           // 256
    float* msr  = scr + 6464;           // 128
    float* h1r  = scr + 6592;           // 256 (end 6848)
    for (int u = tid; u < HD * (HD + MD); u += BLK) {
        const int o = u / (HD + MD), c = u - o * (HD + MD);
        wbig[o * 97 + c] = wf[u];
    }
    h0r[tid] = h0[n0 * HD + tid];
    if (tid < 4 * MD) msr[tid] = ms1[n0 * MD + tid];
    __syncthreads();
    {
        const int nl = tid >> 6, o = tid & 63;
        const float* w  = wbig + o * 97;           // stride 97: conflict-free
        const float* hh = h0r + nl * HD;
        const float* mm = msr + nl * MD;
        float s = bf[o];
#pragma unroll
        for (int c = 0; c < HD; c++) s = fmaf(hh[c], w[c], s);
#pragma unroll
        for (int c = 0; c < MD; c++) s = fmaf(mm[c], w[HD + c], s);
        h1r[tid] = fmaxf(s, 0.f);
    }
    __syncthreads();
    for (int u = tid; u < MD * WROW; u += BLK) wbig[u] = wmsg[u];   // 4128 < 6208
    __syncthreads();
    if (tid < 4 * MD) {
        const int nl = tid >> 5, m = tid & 31;
        const float* wa = wbig + m * WROW;
        const float* hr = h1r + nl * HD;
        float sa = 0.f, sb = bmsg[m];
#pragma unroll
        for (int c = 0; c < HD; c++) {
            const float hv = hr[c];
            sa = fmaf(hv, wa[c], sa);
            sb = fmaf(hv, wa[HD + c], sb);
        }
        const int n = n0 + nl;
        A[n * MD + m]  = sa;
        Bb[n * MD + m] = sb;
    }
}

// ---------------------------------------------------------------------------
// Pair kernel, UNPAIRED: one block (512 thr = 8 waves) per row i.
// Grid = 1024 blocks -> 4 blocks/CU -> 32 waves/CU = 8 waves/SIMD (max TLP).
// Wave w owns j in [w*128, w*128+128). Lane map: kq = lane>>3 (4 k's via one
// float4 A-load), jslot = lane&7 (8 j per wave-iter).
// m = relu(A[j][k] + Bi[k] + d2*wd[k]);  P[k][c] += m * r_c ; wp folded after.
// x_out[i] = x[i] + (S_k wp_ck P_kc + bp_c (Sx_c - N x_ic)) / (N-1)
// LAYER1 also writes diag-corrected msum row i.
// ---------------------------------------------------------------------------
template<int LAYER1>
__global__ __launch_bounds__(BLKP, 8) void k_pair(
    const float* __restrict__ xsrc, const float* __restrict__ Aap,
    const float* __restrict__ Bbp, const float* __restrict__ wmsg,
    const float* __restrict__ wpos, const float* __restrict__ bpos,
    float* __restrict__ xout, float* __restrict__ msout)
{
    const int tid   = threadIdx.x;
    const int wid   = tid >> 6;         // 0..7
    const int lane  = tid & 63;
    const int jslot = lane & 7;
    const int kq    = lane >> 3;        // k = kq*4 .. kq*4+3

    __shared__ float4 rd[N];            // 16 KB
    __shared__ float  sxacc[8][3];
    __shared__ float  wacc[8][3];
    __shared__ float  msl[8][MD];       // LAYER1 only (1 KB)

    const int i = blockIdx.x;
    const float xi0 = xsrc[i * 3 + 0], xi1 = xsrc[i * 3 + 1], xi2 = xsrc[i * 3 + 2];

    // ---- stage r/d2 table; accumulate column-sum of x ----
    float sx0 = 0.f, sx1 = 0.f, sx2 = 0.f;
#pragma unroll
    for (int q = 0; q < N / BLKP; q++) {
        const int j = q * BLKP + tid;
        const float xj0 = xsrc[j * 3 + 0];
        const float xj1 = xsrc[j * 3 + 1];
        const float xj2 = xsrc[j * 3 + 2];
        sx0 += xj0; sx1 += xj1; sx2 += xj2;
        const float r0 = xj0 - xi0, r1 = xj1 - xi1, r2 = xj2 - xi2;
        rd[j] = make_float4(r0, r1, r2, fmaf(r0, r0, fmaf(r1, r1, r2 * r2)));
    }
#pragma unroll
    for (int off = 32; off > 0; off >>= 1) {
        sx0 += __shfl_xor(sx0, off);
        sx1 += __shfl_xor(sx1, off);
        sx2 += __shfl_xor(sx2, off);
    }
    if (lane == 0) { sxacc[wid][0] = sx0; sxacc[wid][1] = sx1; sxacc[wid][2] = sx2; }

    // ---- per-lane weights for the 4 owned k's ----
    const float4 bi4  = *(const float4*)(Bbp + i * MD + kq * 4);
    const float4 wpx4 = *(const float4*)(wpos + kq * 4);
    const float4 wpy4 = *(const float4*)(wpos + MD + kq * 4);
    const float4 wpz4 = *(const float4*)(wpos + 2 * MD + kq * 4);
    float wd4[4];
#pragma unroll
    for (int kk = 0; kk < 4; kk++) wd4[kk] = wmsg[(kq * 4 + kk) * WROW + 2 * HD];
    const float bi[4]  = {bi4.x, bi4.y, bi4.z, bi4.w};
    const float wpx[4] = {wpx4.x, wpx4.y, wpx4.z, wpx4.w};
    const float wpy[4] = {wpy4.x, wpy4.y, wpy4.z, wpy4.w};
    const float wpz[4] = {wpz4.x, wpz4.y, wpz4.z, wpz4.w};

    float Px[4] = {0,0,0,0}, Py[4] = {0,0,0,0}, Pz[4] = {0,0,0,0};
    float ms[4] = {0,0,0,0};

    __syncthreads();                    // rd table ready

    const int jb = wid * (N / 8);       // 128 j per wave
#pragma unroll 4
    for (int it = 0; it < N / 8 / 8; it++) {
        const int j = jb + it * 8 + jslot;
        const float4 a4 = *(const float4*)(Aap + j * MD + kq * 4);  // 1KB/wave coalesced
        const float4 f  = rd[j];        // 8-way broadcast per address
        const float av[4] = {a4.x, a4.y, a4.z, a4.w};
#pragma unroll
        for (int kk = 0; kk < 4; kk++) {
            const float m = fmaxf(fmaf(f.w, wd4[kk], av[kk] + bi[kk]), 0.f);
            if (LAYER1) ms[kk] += m;
            Px[kk] = fmaf(m, f.x, Px[kk]);
            Py[kk] = fmaf(m, f.y, Py[kk]);
            Pz[kk] = fmaf(m, f.z, Pz[kk]);
        }
    }

    // ---- fold wp per lane, then reduce across 64 lanes ----
    float v0 = 0.f, v1 = 0.f, v2 = 0.f;
#pragma unroll
    for (int kk = 0; kk < 4; kk++) {
        v0 = fmaf(Px[kk], wpx[kk], v0);
        v1 = fmaf(Py[kk], wpy[kk], v1);
        v2 = fmaf(Pz[kk], wpz[kk], v2);
    }
#pragma unroll
    for (int off = 32; off > 0; off >>= 1) {
        v0 += __shfl_xor(v0, off);
        v1 += __shfl_xor(v1, off);
        v2 += __shfl_xor(v2, off);
    }
    if (LAYER1) {
        // reduce msum over the 8 jslots (lane bits 0..2)
#pragma unroll
        for (int off = 1; off <= 4; off <<= 1) {
#pragma unroll
            for (int kk = 0; kk < 4; kk++) ms[kk] += __shfl_xor(ms[kk], off);
        }
    }
    if (lane == 0) { wacc[wid][0] = v0; wacc[wid][1] = v1; wacc[wid][2] = v2; }
    if (LAYER1 && jslot == 0) {
#pragma unroll
        for (int kk = 0; kk < 4; kk++) msl[wid][kq * 4 + kk] = ms[kk];
    }
    __syncthreads();                    // epilogue data ready

    if (tid == 0) {
        float a0 = 0.f, a1 = 0.f, a2 = 0.f, s0 = 0.f, s1 = 0.f, s2 = 0.f;
#pragma unroll
        for (int w = 0; w < 8; w++) {
            a0 += wacc[w][0]; a1 += wacc[w][1]; a2 += wacc[w][2];
            s0 += sxacc[w][0]; s1 += sxacc[w][1]; s2 += sxacc[w][2];
        }
        const float inv = 1.0f / 1023.0f;
        xout[i * 3 + 0] = xi0 + (a0 + bpos[0] * (s0 - (float)N * xi0)) * inv;
        xout[i * 3 + 1] = xi1 + (a1 + bpos[1] * (s1 - (float)N * xi1)) * inv;
        xout[i * 3 + 2] = xi2 + (a2 + bpos[2] * (s2 - (float)N * xi2)) * inv;
    }
    if (LAYER1 && tid < MD) {
        float s = 0.f;
#pragma unroll
        for (int w = 0; w < 8; w++) s += msl[w][tid];
        // remove diagonal contribution (d2 = 0 at j == i)
        s -= fmaxf(Aap[i * MD + tid] + Bbp[i * MD + tid], 0.f);
        msout[i * MD + tid] = s;
    }
}

// ---------------------------------------------------------------------------
extern "C" void kernel_launch(void* const* d_in, const int* in_sizes, int n_in,
                              void* d_out, int out_size, void* d_ws, size_t ws_size,
                              hipStream_t stream)
{
    const float* pos     = (const float*)d_in[0];
    const float* feat    = (const float*)d_in[1];
    const float* w_msg1  = (const float*)d_in[3];
    const float* b_msg1  = (const float*)d_in[4];
    const float* w_pos1  = (const float*)d_in[5];
    const float* b_pos1  = (const float*)d_in[6];
    const float* w_feat1 = (const float*)d_in[7];
    const float* b_feat1 = (const float*)d_in[8];
    const float* w_msg2  = (const float*)d_in[9];
    const float* b_msg2  = (const float*)d_in[10];
    const float* w_pos2  = (const float*)d_in[11];
    const float* b_pos2  = (const float*)d_in[12];

    float* ws  = (float*)d_ws;
    float* h0  = ws;                 // N*HD
    float* A1  = h0  + N * HD;       // N*MD
    float* B1  = A1  + N * MD;
    float* x1  = B1  + N * MD;       // N*4 (padded)
    float* ms1 = x1  + N * 4;
    float* A2  = ms1 + N * MD;
    float* B2  = A2  + N * MD;

    k_p0<<<N / 4, BLK, 0, stream>>>(feat, w_msg1, b_msg1, h0, A1, B1);
    k_pair<1><<<N, BLKP, 0, stream>>>(pos, A1, B1, w_msg1, w_pos1, b_pos1, x1, ms1);
    k_p2<<<N / 4, BLK, 0, stream>>>(h0, ms1, w_feat1, b_feat1, w_msg2, b_msg2, A2, B2);
    k_pair<0><<<N, BLKP, 0, stream>>>(x1, A2, B2, w_msg2, w_pos2, b_pos2,
                                      (float*)d_out, nullptr);
}

// Round 13
// 46.167 us; speedup vs baseline: 2.6729x; 1.2167x over previous
//
#include <hip/hip_runtime.h>

#define N    1024
#define HD   64
#define MD   32
#define BLK  256        // k_p0 / k_p2 block
#define BLKP 1024       // pair block: 16 waves, 1 block/CU, 4 waves/SIMD
#define RPB  4          // rows per pair block -> A-traffic = 256*128KB = 34 MB
#define WROW (2 * HD + 1)   // 129, w_msg row stride

// ---------------------------------------------------------------------------
// P0: h0 = feat + posenc; A1/B1 projections. One block per 4 rows.
// ---------------------------------------------------------------------------
__global__ __launch_bounds__(BLK) void k_p0(const float* __restrict__ feat,
                                            const float* __restrict__ wmsg,
                                            const float* __restrict__ bmsg,
                                            float* __restrict__ h0,
                                            float* __restrict__ A,
                                            float* __restrict__ Bb)
{
    __shared__ float scr[4160 + 4 * HD];
    const int tid = threadIdx.x;
    const int n0  = blockIdx.x * 4;

    for (int u = tid; u < MD * WROW; u += BLK) scr[u] = wmsg[u];   // 4128 floats
    float* hrow = scr + 4160;
    {
        const int n = n0 + (tid >> 6), d = tid & 63;
        const float div = expf((float)(d & ~1) * (-9.210340371976184f / 64.0f));
        const float ang = (float)n * div;
        const float pe  = (d & 1) ? cosf(ang) : sinf(ang);
        const float hv  = feat[n * HD + d] + pe;
        h0[n * HD + d] = hv;
        hrow[tid] = hv;
    }
    __syncthreads();
    if (tid < 4 * MD) {
        const int nl = tid >> 5, m = tid & 31;
        const float* wa = scr + m * WROW;          // stride 129: conflict-free
        const float* hr = hrow + nl * HD;
        float sa = 0.f, sb = bmsg[m];
#pragma unroll
        for (int c = 0; c < HD; c++) {
            const float hv = hr[c];
            sa = fmaf(hv, wa[c], sa);
            sb = fmaf(hv, wa[HD + c], sb);
        }
        const int n = n0 + nl;
        A[n * MD + m]  = sa;
        Bb[n * MD + m] = sb;
    }
}

// ---------------------------------------------------------------------------
// P2: h1 = relu([h0, ms1] @ wf.T + bf); A2/B2 projections. One block per 4 rows.
// ---------------------------------------------------------------------------
__global__ __launch_bounds__(BLK) void k_p2(const float* __restrict__ h0,
                                            const float* __restrict__ ms1,
                                            const float* __restrict__ wf,
                                            const float* __restrict__ bf,
                                            const float* __restrict__ wmsg,
                                            const float* __restrict__ bmsg,
                                            float* __restrict__ A,
                                            float* __restrict__ Bb)
{
    __shared__ float scr[6848];
    const int tid = threadIdx.x;
    const int n0  = blockIdx.x * 4;

    float* wbig = scr;                  // 64 rows, padded stride 97 -> 6208
    float* h0r  = scr + 6208;           // 256
    float* msr  = scr + 6464;           // 128
    float* h1r  = scr + 6592;           // 256 (end 6848)
    for (int u = tid; u < HD * (HD + MD); u += BLK) {
        const int o = u / (HD + MD), c = u - o * (HD + MD);
        wbig[o * 97 + c] = wf[u];
    }
    h0r[tid] = h0[n0 * HD + tid];
    if (tid < 4 * MD) msr[tid] = ms1[n0 * MD + tid];
    __syncthreads();
    {
        const int nl = tid >> 6, o = tid & 63;
        const float* w  = wbig + o * 97;           // stride 97: conflict-free
        const float* hh = h0r + nl * HD;
        const float* mm = msr + nl * MD;
        float s = bf[o];
#pragma unroll
        for (int c = 0; c < HD; c++) s = fmaf(hh[c], w[c], s);
#pragma unroll
        for (int c = 0; c < MD; c++) s = fmaf(mm[c], w[HD + c], s);
        h1r[tid] = fmaxf(s, 0.f);
    }
    __syncthreads();
    for (int u = tid; u < MD * WROW; u += BLK) wbig[u] = wmsg[u];   // 4128 < 6208
    __syncthreads();
    if (tid < 4 * MD) {
        const int nl = tid >> 5, m = tid & 31;
        const float* wa = wbig + m * WROW;
        const float* hr = h1r + nl * HD;
        float sa = 0.f, sb = bmsg[m];
#pragma unroll
        for (int c = 0; c < HD; c++) {
            const float hv = hr[c];
            sa = fmaf(hv, wa[c], sa);
            sb = fmaf(hv, wa[HD + c], sb);
        }
        const int n = n0 + nl;
        A[n * MD + m]  = sa;
        Bb[n * MD + m] = sb;
    }
}

// ---------------------------------------------------------------------------
// Pair kernel: one block (1024 thr = 16 waves) per 4 rows (i0..i0+3).
// Grid 256 -> 1 block/CU, 4 waves/SIMD. Each A-row float4 load is shared by
// 4 output rows -> A-traffic 34 MB/kernel (L3-bound term halved vs best).
// Wave w owns j in [w*64, w*64+64). Lane: kq = lane>>3 (4 k's), jslot = lane&7.
// m = relu(A[j][k] + Bi[k] + d2*wd[k]);  v_c += (m*wp_ck)*r_c  (wp folded in).
// x_out[i] = x[i] + (v_c + bp_c (Sx_c - N x_ic)) / (N-1)
// LAYER1 also writes diag-corrected msum rows.
// ---------------------------------------------------------------------------
template<int LAYER1>
__global__ __launch_bounds__(BLKP) void k_pair(
    const float* __restrict__ xsrc, const float* __restrict__ Aap,
    const float* __restrict__ Bbp, const float* __restrict__ wmsg,
    const float* __restrict__ wpos, const float* __restrict__ bpos,
    float* __restrict__ xout, float* __restrict__ msout)
{
    const int tid   = threadIdx.x;
    const int wid   = tid >> 6;         // 0..15
    const int lane  = tid & 63;
    const int jslot = lane & 7;
    const int kq    = lane >> 3;        // k = kq*4 .. kq*4+3

    __shared__ float4 rd[RPB][N];                   // 64 KB
    __shared__ float  sxacc[16][3];
    __shared__ float  vacc[16][RPB][3];
    __shared__ float  msl[LAYER1 ? 16 : 1][RPB][MD]; // 8 KB when LAYER1

    const int i0 = blockIdx.x * RPB;

    float xi[RPB][3];
#pragma unroll
    for (int r = 0; r < RPB; r++)
#pragma unroll
        for (int c = 0; c < 3; c++) xi[r][c] = xsrc[(i0 + r) * 3 + c];

    // ---- stage r/d2 tables for 4 rows (1 j per thread); Sx partial ----
    {
        const int j = tid;
        const float xj0 = xsrc[j * 3 + 0];
        const float xj1 = xsrc[j * 3 + 1];
        const float xj2 = xsrc[j * 3 + 2];
        float sx0 = xj0, sx1 = xj1, sx2 = xj2;
#pragma unroll
        for (int r = 0; r < RPB; r++) {
            const float r0 = xj0 - xi[r][0], r1 = xj1 - xi[r][1], r2 = xj2 - xi[r][2];
            rd[r][j] = make_float4(r0, r1, r2, fmaf(r0, r0, fmaf(r1, r1, r2 * r2)));
        }
#pragma unroll
        for (int off = 32; off > 0; off >>= 1) {
            sx0 += __shfl_xor(sx0, off);
            sx1 += __shfl_xor(sx1, off);
            sx2 += __shfl_xor(sx2, off);
        }
        if (lane == 0) { sxacc[wid][0] = sx0; sxacc[wid][1] = sx1; sxacc[wid][2] = sx2; }
    }

    // ---- per-lane weights for the 4 owned k's ----
    float bi[RPB][4];
#pragma unroll
    for (int r = 0; r < RPB; r++) {
        const float4 b4 = *(const float4*)(Bbp + (i0 + r) * MD + kq * 4);
        bi[r][0] = b4.x; bi[r][1] = b4.y; bi[r][2] = b4.z; bi[r][3] = b4.w;
    }
    const float4 wpx4 = *(const float4*)(wpos + kq * 4);
    const float4 wpy4 = *(const float4*)(wpos + MD + kq * 4);
    const float4 wpz4 = *(const float4*)(wpos + 2 * MD + kq * 4);
    float wd4[4];
#pragma unroll
    for (int kk = 0; kk < 4; kk++) wd4[kk] = wmsg[(kq * 4 + kk) * WROW + 2 * HD];
    const float wpx[4] = {wpx4.x, wpx4.y, wpx4.z, wpx4.w};
    const float wpy[4] = {wpy4.x, wpy4.y, wpy4.z, wpy4.w};
    const float wpz[4] = {wpz4.x, wpz4.y, wpz4.z, wpz4.w};

    float v[RPB][3];
    float ms[RPB][4];
#pragma unroll
    for (int r = 0; r < RPB; r++) {
        v[r][0] = v[r][1] = v[r][2] = 0.f;
        ms[r][0] = ms[r][1] = ms[r][2] = ms[r][3] = 0.f;
    }

    __syncthreads();                    // rd tables ready

    const int jb = wid * (N / 16);      // 64 j per wave
#pragma unroll 2
    for (int it = 0; it < 8; it++) {
        const int j = jb + it * 8 + jslot;
        const float4 a4 = *(const float4*)(Aap + j * MD + kq * 4);  // 1KB/wave, shared by 4 rows
        const float av[4] = {a4.x, a4.y, a4.z, a4.w};
#pragma unroll
        for (int r = 0; r < RPB; r++) {
            const float4 f = rd[r][j];  // 8-way broadcast per address
#pragma unroll
            for (int kk = 0; kk < 4; kk++) {
                const float m = fmaxf(fmaf(f.w, wd4[kk], av[kk] + bi[r][kk]), 0.f);
                if (LAYER1) ms[r][kk] += m;
                v[r][0] = fmaf(m * wpx[kk], f.x, v[r][0]);
                v[r][1] = fmaf(m * wpy[kk], f.y, v[r][1]);
                v[r][2] = fmaf(m * wpz[kk], f.z, v[r][2]);
            }
        }
    }

    // ---- reduce v across 64 lanes (sums jslot and kq) ----
#pragma unroll
    for (int off = 32; off > 0; off >>= 1)
#pragma unroll
        for (int r = 0; r < RPB; r++) {
            v[r][0] += __shfl_xor(v[r][0], off);
            v[r][1] += __shfl_xor(v[r][1], off);
            v[r][2] += __shfl_xor(v[r][2], off);
        }
    if (LAYER1) {
        // reduce msum over the 8 jslots only (k stays per-lane)
#pragma unroll
        for (int off = 1; off <= 4; off <<= 1)
#pragma unroll
            for (int r = 0; r < RPB; r++)
#pragma unroll
                for (int kk = 0; kk < 4; kk++) ms[r][kk] += __shfl_xor(ms[r][kk], off);
    }
    if (lane == 0)
#pragma unroll
        for (int r = 0; r < RPB; r++) {
            vacc[wid][r][0] = v[r][0];
            vacc[wid][r][1] = v[r][1];
            vacc[wid][r][2] = v[r][2];
        }
    if (LAYER1 && jslot == 0)
#pragma unroll
        for (int r = 0; r < RPB; r++)
#pragma unroll
            for (int kk = 0; kk < 4; kk++) msl[wid][r][kq * 4 + kk] = ms[r][kk];
    __syncthreads();                    // epilogue data ready

    if (tid < RPB * 3) {
        const int r = tid / 3, c = tid - r * 3;
        float a = 0.f, s = 0.f;
#pragma unroll
        for (int w = 0; w < 16; w++) { a += vacc[w][r][c]; s += sxacc[w][c]; }
        const int i = i0 + r;
        const float x0 = xi[r][c];
        xout[i * 3 + c] = x0 + (a + bpos[c] * (s - (float)N * x0)) * (1.0f / 1023.0f);
    }
    if (LAYER1 && tid < RPB * MD) {
        const int r = tid >> 5, k = tid & 31;
        float s = 0.f;
#pragma unroll
        for (int w = 0; w < 16; w++) s += msl[w][r][k];
        const int i = i0 + r;
        // remove diagonal contribution (d2 = 0 at j == i)
        s -= fmaxf(Aap[i * MD + k] + Bbp[i * MD + k], 0.f);
        msout[i * MD + k] = s;
    }
}

// ---------------------------------------------------------------------------
extern "C" void kernel_launch(void* const* d_in, const int* in_sizes, int n_in,
                              void* d_out, int out_size, void* d_ws, size_t ws_size,
                              hipStream_t stream)
{
    const float* pos     = (const float*)d_in[0];
    const float* feat    = (const float*)d_in[1];
    const float* w_msg1  = (const float*)d_in[3];
    const float* b_msg1  = (const float*)d_in[4];
    const float* w_pos1  = (const float*)d_in[5];
    const float* b_pos1  = (const float*)d_in[6];
    const float* w_feat1 = (const float*)d_in[7];
    const float* b_feat1 = (const float*)d_in[8];
    const float* w_msg2  = (const float*)d_in[9];
    const float* b_msg2  = (const float*)d_in[10];
    const float* w_pos2  = (const float*)d_in[11];
    const float* b_pos2  = (const float*)d_in[12];

    float* ws  = (float*)d_ws;
    float* h0  = ws;                 // N*HD
    float* A1  = h0  + N * HD;       // N*MD
    float* B1  = A1  + N * MD;
    float* x1  = B1  + N * MD;       // N*4 (padded)
    float* ms1 = x1  + N * 4;
    float* A2  = ms1 + N * MD;
    float* B2  = A2  + N * MD;

    k_p0<<<N / 4, BLK, 0, stream>>>(feat, w_msg1, b_msg1, h0, A1, B1);
    k_pair<1><<<N / RPB, BLKP, 0, stream>>>(pos, A1, B1, w_msg1, w_pos1, b_pos1, x1, ms1);
    k_p2<<<N / 4, BLK, 0, stream>>>(h0, ms1, w_feat1, b_feat1, w_msg2, b_msg2, A2, B2);
    k_pair<0><<<N / RPB, BLKP, 0, stream>>>(x1, A2, B2, w_msg2, w_pos2, b_pos2,
                                            (float*)d_out, nullptr);
}